// Round 6
// baseline (587.298 us; speedup 1.0000x reference)
//
#include <hip/hip_runtime.h>
#include <hip/hip_bf16.h>
#include <stdint.h>

// ---- types ----
typedef __bf16 bf16x8 __attribute__((ext_vector_type(8)));
typedef float  floatx4 __attribute__((ext_vector_type(4)));

#define NEG_BIG (-1e30f)   // finite sentinel: exp(NEG_BIG - m) == 0

// async global->LDS, 16B per lane; LDS dest = wave-uniform base + lane*16
#define GLD16(g, l) __builtin_amdgcn_global_load_lds(                         \
    (__attribute__((address_space(1))) void*)(g),                             \
    (__attribute__((address_space(3))) void*)(l), 16, 0, 0)

// convert 16 fp32 -> 16 bf16, store 32B to LDS
__device__ __forceinline__ void cvt16(const float* __restrict__ s,
                                      __hip_bfloat16* __restrict__ d) {
    float4 f[4];
#pragma unroll
    for (int i = 0; i < 4; i++) f[i] = ((const float4*)s)[i];
    union { __hip_bfloat16 h[16]; uint4 u[2]; } o;
#pragma unroll
    for (int i = 0; i < 4; i++) {
        o.h[4 * i + 0] = __float2bfloat16(f[i].x);
        o.h[4 * i + 1] = __float2bfloat16(f[i].y);
        o.h[4 * i + 2] = __float2bfloat16(f[i].z);
        o.h[4 * i + 3] = __float2bfloat16(f[i].w);
    }
    ((uint4*)d)[0] = o.u[0];
    ((uint4*)d)[1] = o.u[1];
}

// ============================================================================
// NT GEMM: C[M,N] = A[M,K] * B[N,K]^T + bias[N].  A fp32/bf16 (template),
// B fp32 (fused convert), fp32 bias. OUT_F32: C stored fp32 (the final
// output buffer is float32 per the reference!) else bf16.
// 128x128 tile, BK=32, 256 threads (4 waves, 2x2 wave grid, 4x4 MFMAs each).
// ============================================================================
template <bool A_F32, bool B_F32, bool OUT_F32>
__global__ __launch_bounds__(256, 2)
void gemm_nt_bias(const void* __restrict__ Av, const void* __restrict__ Bv,
                  const float* __restrict__ bias, void* __restrict__ Cv,
                  int M, int N, int K, int lda, int ldb)
{
    __shared__ __align__(16) __hip_bfloat16 Asm[128 * 32];
    __shared__ __align__(16) __hip_bfloat16 Bsm[128 * 32];
    const int m0   = blockIdx.y * 128;
    const int n0   = blockIdx.x * 128;
    const int t    = threadIdx.x;
    const int wave = t >> 6, lane = t & 63;
    const int quad = lane >> 4, l16 = lane & 15;
    const int wr   = wave >> 1, wc = wave & 1;   // wave sub-tile 64x64

    floatx4 zero = {0.f, 0.f, 0.f, 0.f};
    floatx4 acc[4][4];
    for (int i = 0; i < 4; i++)
        for (int j = 0; j < 4; j++) acc[i][j] = zero;

    for (int k0 = 0; k0 < K; k0 += 32) {
        // ---- stage A tile (128 x 32) ----
        if (A_F32) {
            const float* A = (const float*)Av;
            const int row = t >> 1, half = t & 1;     // 16 floats per thread
            cvt16(A + (size_t)(m0 + row) * lda + k0 + half * 16,
                  Asm + row * 32 + half * 16);
        } else {
            const __hip_bfloat16* A = (const __hip_bfloat16*)Av;
            for (int j = 0; j < 2; ++j) {
                const int chunk = (wave * 2 + j) * 64 + lane;   // 0..511
                const int row   = chunk >> 2;
                const int kc    = chunk & 3;
                GLD16(A + (size_t)(m0 + row) * lda + k0 + kc * 8,
                      Asm + (wave * 2 + j) * 512);
            }
        }
        // ---- stage B tile (128 x 32) ----
        if (B_F32) {
            const float* B = (const float*)Bv;
            const int row = t >> 1, half = t & 1;
            cvt16(B + (size_t)(n0 + row) * ldb + k0 + half * 16,
                  Bsm + row * 32 + half * 16);
        } else {
            const __hip_bfloat16* B = (const __hip_bfloat16*)Bv;
            for (int j = 0; j < 2; ++j) {
                const int chunk = (wave * 2 + j) * 64 + lane;
                const int row   = chunk >> 2;
                const int kc    = chunk & 3;
                GLD16(B + (size_t)(n0 + row) * ldb + k0 + kc * 8,
                      Bsm + (wave * 2 + j) * 512);
            }
        }
        __syncthreads();

        bf16x8 af[4], bf[4];
        for (int i = 0; i < 4; i++) {
            af[i] = *(const bf16x8*)(Asm + (wr * 64 + i * 16 + l16) * 32 + quad * 8);
            bf[i] = *(const bf16x8*)(Bsm + (wc * 64 + i * 16 + l16) * 32 + quad * 8);
        }
        for (int mi = 0; mi < 4; mi++)
            for (int ni = 0; ni < 4; ni++)
                acc[mi][ni] = __builtin_amdgcn_mfma_f32_16x16x32_bf16(
                    af[mi], bf[ni], acc[mi][ni], 0, 0, 0);
        __syncthreads();
    }

    // epilogue: C/D layout row = quad*4 + reg, col = l16
    for (int mi = 0; mi < 4; mi++) {
        const int row = m0 + wr * 64 + mi * 16 + quad * 4;
        for (int ni = 0; ni < 4; ni++) {
            const int col = n0 + wc * 64 + ni * 16 + l16;
            const float bv = bias[col];
            for (int r = 0; r < 4; r++) {
                const float v = acc[mi][ni][r] + bv;
                if (OUT_F32)
                    ((float*)Cv)[(size_t)(row + r) * N + col] = v;
                else
                    ((__hip_bfloat16*)Cv)[(size_t)(row + r) * N + col] =
                        __float2bfloat16(v);
            }
        }
    }
}

// ============================================================================
// V permutation (module's double-reshape):
//   V[b,h,s',d'] = v0[b, (s'&7)*128 + h*8 + (d'>>4), (s'>>3)*16 + (d'&15)]
// v0 = QKV cols [4096,6144). Output blocked+transposed:
//   Vpt[b][h][sb][hd][ss]  (sb = s'/32, ss = s'%32) -> each kv tile contiguous.
// ============================================================================
__global__ __launch_bounds__(256)
void permute_v(const __hip_bfloat16* __restrict__ QKV,
               __hip_bfloat16* __restrict__ Vpt)
{
    __shared__ __align__(16) __hip_bfloat16 S[64 * 64];
    const int blk = blockIdx.x;
    const int sb = blk & 31, h = (blk >> 5) & 15, b = blk >> 9;
    const int t = threadIdx.x;

    for (int j = 0; j < 2; j++) {
        const int chunk = j * 256 + t;          // 0..511 (16B each)
        const int lrow  = chunk >> 3;           // 8 chunks per 64-elem row
        const int lcol  = (chunk & 7) * 8;
        const int r8 = lrow >> 3, jj = lrow & 7;
        const int srow = r8 * 128 + h * 8 + jj;
        const int scol = sb * 64 + lcol;
        *(uint4*)(S + chunk * 8) =
            *(const uint4*)(QKV + ((size_t)(b * 1024) + srow) * 6144 + 4096 + scol);
    }
    __syncthreads();

    const size_t obase = (((size_t)(b * 16 + h)) * 32 + sb) * 4096;
    for (int i = 0; i < 16; i++) {
        const int lin = t + 256 * i;            // coalesced writes
        const int hd = lin >> 5, ss = lin & 31;
        Vpt[obase + lin] =
            S[((ss & 7) * 8 + (hd >> 4)) * 64 + (ss >> 3) * 16 + (hd & 15)];
    }
}

// ============================================================================
// Causal flash attention. Block = 64 q-rows (4 waves x 16), kv tile = 32.
// Q,K from QKV; V from Vpt. Output into QKV's dead V-columns (stride 6144,
// col offset 4096) -- those columns are never read again (Vpt holds V).
// ============================================================================
__global__ __launch_bounds__(256, 2)
void flash_attn(const __hip_bfloat16* __restrict__ QKV,
                const __hip_bfloat16* __restrict__ Vpt,
                __hip_bfloat16* __restrict__ O)   // == QKV buffer
{
    __shared__ __align__(16) __hip_bfloat16 Kt[32 * 128];  // [kv][hd]
    __shared__ __align__(16) __hip_bfloat16 Vt[128 * 32];  // [hd][kv]
    __shared__ __align__(16) __hip_bfloat16 Pl[64 * 32];   // [qrow][kv]
    const int b = blockIdx.y >> 4, h = blockIdx.y & 15;
    const int qb = blockIdx.x * 64;
    const int t = threadIdx.x;
    const int wave = t >> 6, lane = t & 63;
    const int quad = lane >> 4, l16 = lane & 15;
    const float scale = 0.08838834764831845f;   // 128^-0.5

    // Q fragments (A-layout: row=l16, k=quad*8+j), direct from global
    bf16x8 qf[4];
    {
        const size_t rb = ((size_t)(b * 1024) + qb + wave * 16 + l16) * 6144 + h * 128;
        for (int kc = 0; kc < 4; kc++)
            qf[kc] = *(const bf16x8*)(QKV + rb + kc * 32 + quad * 8);
    }

    float m_i[4], l_i[4];
    floatx4 zero = {0.f, 0.f, 0.f, 0.f};
    floatx4 oacc[8];
    for (int r = 0; r < 4; r++) { m_i[r] = NEG_BIG; l_i[r] = 0.f; }
    for (int ni = 0; ni < 8; ni++) oacc[ni] = zero;

    const int ntiles = qb / 32 + 2;             // causal bound
    for (int tk = 0; tk < ntiles; ++tk) {
        const int kv0 = tk * 32;
        __syncthreads();
        // stage K tile: 32 rows x 128 elems = 512 x 16B chunks
        for (int j = 0; j < 2; j++) {
            const int chunk = (wave * 2 + j) * 64 + lane;
            const int row = chunk >> 4;
            const int kc  = chunk & 15;
            GLD16(QKV + ((size_t)(b * 1024) + kv0 + row) * 6144 + 2048 + h * 128 + kc * 8,
                  Kt + (wave * 2 + j) * 512);
        }
        // stage V tile: contiguous 8KB blob
        {
            const __hip_bfloat16* g = Vpt + ((((size_t)(b * 16 + h)) * 32) + tk) * 4096;
            for (int j = 0; j < 2; j++) {
                const int chunk = (wave * 2 + j) * 64 + lane;
                GLD16(g + chunk * 8, Vt + (wave * 2 + j) * 512);
            }
        }
        __syncthreads();

        // Sc = Q K^T  (2 col-blocks of 16, K=128 via 4 MFMAs)
        floatx4 sc[2];
        for (int cb = 0; cb < 2; cb++) {
            floatx4 s = zero;
            for (int kc = 0; kc < 4; kc++) {
                bf16x8 kf = *(const bf16x8*)(Kt + (cb * 16 + l16) * 128 + kc * 32 + quad * 8);
                s = __builtin_amdgcn_mfma_f32_16x16x32_bf16(qf[kc], kf, s, 0, 0, 0);
            }
            sc[cb] = s;
        }

        // scale + causal mask (finite sentinel)
        float tmax[4];
        for (int r = 0; r < 4; r++) {
            const int qrow = qb + wave * 16 + quad * 4 + r;
            for (int cb = 0; cb < 2; cb++) {
                const int col = kv0 + cb * 16 + l16;
                const float v = sc[cb][r] * scale;
                sc[cb][r] = (col > qrow) ? NEG_BIG : v;
            }
            tmax[r] = fmaxf(sc[0][r], sc[1][r]);
        }
        for (int off = 1; off < 16; off <<= 1)
            for (int r = 0; r < 4; r++)
                tmax[r] = fmaxf(tmax[r], __shfl_xor(tmax[r], off));

        float alpha[4], rsum[4];
        for (int r = 0; r < 4; r++) {
            const float mnew = fmaxf(m_i[r], tmax[r]);
            alpha[r] = __expf(m_i[r] - mnew);   // first tile: exp(-1e30) == 0
            const float p0 = __expf(sc[0][r] - mnew);
            const float p1 = __expf(sc[1][r] - mnew);
            sc[0][r] = p0; sc[1][r] = p1;
            rsum[r] = p0 + p1;
            m_i[r] = mnew;
        }
        for (int off = 1; off < 16; off <<= 1)
            for (int r = 0; r < 4; r++)
                rsum[r] += __shfl_xor(rsum[r], off);
        for (int r = 0; r < 4; r++) l_i[r] = l_i[r] * alpha[r] + rsum[r];
        for (int ni = 0; ni < 8; ni++)
            for (int r = 0; r < 4; r++) oacc[ni][r] *= alpha[r];

        // P -> LDS (C-layout write, A-layout read)
        for (int cb = 0; cb < 2; cb++)
            for (int r = 0; r < 4; r++)
                Pl[(wave * 16 + quad * 4 + r) * 32 + cb * 16 + l16] =
                    __float2bfloat16(sc[cb][r]);
        __syncthreads();

        // O += P V : A = P[16x32], B = V[32x128] (from Vt[hd][kv])
        bf16x8 pf = *(const bf16x8*)(Pl + (wave * 16 + l16) * 32 + quad * 8);
        for (int ni = 0; ni < 8; ni++) {
            bf16x8 vf = *(const bf16x8*)(Vt + (ni * 16 + l16) * 32 + quad * 8);
            oacc[ni] = __builtin_amdgcn_mfma_f32_16x16x32_bf16(pf, vf, oacc[ni], 0, 0, 0);
        }
    }

    // epilogue: O into QKV's V-columns (stride 6144, col offset 4096)
    for (int ni = 0; ni < 8; ni++) {
        for (int r = 0; r < 4; r++) {
            const int row = qb + wave * 16 + quad * 4 + r;
            const float v = oacc[ni][r] / l_i[r];
            O[((size_t)(b * 1024) + row) * 6144 + 4096 + h * 128 + ni * 16 + l16] =
                __float2bfloat16(v);
        }
    }
}

// ============================================================================
extern "C" void kernel_launch(void* const* d_in, const int* in_sizes, int n_in,
                              void* d_out, int out_size, void* d_ws, size_t ws_size,
                              hipStream_t stream) {
    const float* query = (const float*)d_in[0];
    // d_in[1] (key), d_in[2] (value) are ignored by the module
    const float* Wqkv = (const float*)d_in[3];
    const float* bqkv = (const float*)d_in[4];
    const float* Wout = (const float*)d_in[5];
    const float* bout = (const float*)d_in[6];
    float* out = (float*)d_out;   // reference output dtype is FLOAT32

    // ws: QKV bf16 48MB @0 (V cols become Att after flash) | Vpt 16MB @48
    char* ws = (char*)d_ws;
    __hip_bfloat16* QKV = (__hip_bfloat16*)ws;
    __hip_bfloat16* Vpt = (__hip_bfloat16*)(ws + (size_t)48 * 1048576);
    __hip_bfloat16* Att = QKV + 4096;            // column offset, lda = 6144

    dim3 blk(256);
    // 1) QKV projection: (4096x2048 f32) @ (6144x2048 f32)^T -> bf16
    gemm_nt_bias<true, true, false><<<dim3(48, 32), blk, 0, stream>>>(
        query, Wqkv, bqkv, QKV, 4096, 6144, 2048, 2048, 2048);
    // 2) V permutation -> blocked/transposed layout
    permute_v<<<dim3(2048), blk, 0, stream>>>(QKV, Vpt);
    // 3) causal flash attention (writes into QKV's dead V columns)
    flash_attn<<<dim3(16, 64), blk, 0, stream>>>(QKV, Vpt, QKV);
    // 4) out projection: Att(4096x2048 bf16, lda 6144) @ (2048x2048 f32)^T -> f32
    gemm_nt_bias<false, true, true><<<dim3(16, 32), blk, 0, stream>>>(
        Att, Wout, bout, out, 4096, 2048, 2048, 6144, 2048);
}